// Round 5
// baseline (695.601 us; speedup 1.0000x reference)
//
#include <hip/hip_runtime.h>
#include <cstdint>
#include <cstddef>

typedef unsigned short u16;
typedef unsigned int u32;
typedef __attribute__((ext_vector_type(8))) __bf16 bf16x8;
typedef __attribute__((ext_vector_type(4))) float f32x4;

#define DEV static __device__ __forceinline__

DEV u16 bf16rne(float f) {
  u32 u = __float_as_uint(f);
  u += 0x7fffu + ((u >> 16) & 1u);
  return (u16)(u >> 16);
}

typedef __attribute__((address_space(1))) void* as1v;
typedef __attribute__((address_space(3))) void* as3v;
DEV void gload16(const void* g, void* l) {
  __builtin_amdgcn_global_load_lds((as1v)g, (as3v)l, 16, 0, 0);
}

// XOR swizzle: spread 8 consecutive rows' same-column 16B chunks across banks
#define SW(r, b) ((b) ^ (((r) & 7) << 4))
#define MFMA16(a, b, c) __builtin_amdgcn_mfma_f32_16x16x32_bf16(a, b, c, 0, 0, 0)

// ---------------------------------------------------------------- small ops
__global__ void cvtx_kernel(const float* __restrict__ src, u16* __restrict__ dst) {
  int i = blockIdx.x * 256 + threadIdx.x;
  float4 v = ((const float4*)src)[i];
  ushort4 o;
  o.x = bf16rne(v.x); o.y = bf16rne(v.y); o.z = bf16rne(v.z); o.w = bf16rne(v.w);
  ((ushort4*)dst)[i] = o;
}

// 2048x2048 f32 -> bf16 transpose (dst[n][k] = src[k][n])
__global__ void wtrans_kernel(const float* __restrict__ src, u16* __restrict__ dst) {
  __shared__ float tile[32][33];
  int bx = blockIdx.x * 32, by = blockIdx.y * 32;
  int tx = threadIdx.x, ty = threadIdx.y;  // (32,8)
#pragma unroll
  for (int k2 = 0; k2 < 4; ++k2)
    tile[ty + k2 * 8][tx] = src[(size_t)(by + ty + k2 * 8) * 2048 + bx + tx];
  __syncthreads();
#pragma unroll
  for (int k2 = 0; k2 < 4; ++k2)
    dst[(size_t)(bx + ty + k2 * 8) * 2048 + by + tx] = bf16rne(tile[tx][ty + k2 * 8]);
}

__global__ void gate_kernel(const float* __restrict__ mask, const float* __restrict__ Wg1,
                            const float* __restrict__ bg1, const float* __restrict__ Wg2,
                            const float* __restrict__ bg2, float* __restrict__ gate) {
  int b = blockIdx.x;
  const float* mb = mask + b * 2048;
  __shared__ float red[256];
  float s = 0.f;
  for (int t = threadIdx.x; t < 2048; t += 256) s += mb[t];
  red[threadIdx.x] = s;
  __syncthreads();
  for (int w = 128; w > 0; w >>= 1) {
    if ((int)threadIdx.x < w) red[threadIdx.x] += red[threadIdx.x + w];
    __syncthreads();
  }
  float mean = red[0] * (1.f / 2048.f);
  float w1a[8], w1b[8], b1[8], w2[32], b2[4];
#pragma unroll
  for (int j = 0; j < 8; ++j) { w1a[j] = Wg1[j]; w1b[j] = Wg1[8 + j]; b1[j] = bg1[j]; }
#pragma unroll
  for (int j = 0; j < 32; ++j) w2[j] = Wg2[j];
#pragma unroll
  for (int g = 0; g < 4; ++g) b2[g] = bg2[g];
  for (int t = threadIdx.x; t < 2048; t += 256) {
    float iq = mb[t];
    float hh[8];
#pragma unroll
    for (int j = 0; j < 8; ++j) {
      float z = iq * w1a[j] + mean * w1b[j] + b1[j];
      hh[j] = z / (1.f + __expf(-z));  // silu
    }
#pragma unroll
    for (int g = 0; g < 4; ++g) {
      float z = b2[g];
#pragma unroll
      for (int j = 0; j < 8; ++j) z += hh[j] * w2[j * 4 + g];
      gate[(size_t)(b * 2048 + t) * 4 + g] = 1.f / (1.f + __expf(-z));
    }
  }
}

// blend[r][h] = sigmoid(x[r,:] . Wb[:,h] + bb[h]); thread per (r,h)
__global__ void blend_kernel(const float* __restrict__ x, const float* __restrict__ Wb,
                             const float* __restrict__ bb, float* __restrict__ blend) {
  int tid = blockIdx.x * 256 + threadIdx.x;
  int h = tid & 15, r = tid >> 4;
  const float* xr = x + (size_t)r * 2048;
  float acc = 0.f;
  for (int d = 0; d < 2048; d += 4) {
    float4 xv = *(const float4*)(xr + d);
    acc += xv.x * Wb[(d + 0) * 16 + h] + xv.y * Wb[(d + 1) * 16 + h] +
           xv.z * Wb[(d + 2) * 16 + h] + xv.w * Wb[(d + 3) * 16 + h];
  }
  blend[tid] = 1.f / (1.f + __expf(-(acc + bb[h])));
}

// ------------------------------------------------------------- 128x128 GEMM
// C[4096][2048] = A[4096][2048] x B (B given as B^T[n][k], both bf16)
// EPI 0: q-projection epilogue (scale by 1/sqrt(128) * gate, write bf16 (B,H,T,DH))
// EPI 1: write f32 C row-major (final out projection)
template <int EPI>
__global__ __launch_bounds__(256) void gemm_bt(const u16* __restrict__ A,
                                               const u16* __restrict__ BT,
                                               const float* __restrict__ gate,
                                               void* __restrict__ outp) {
  __shared__ __align__(16) char sm[32768];
  char* As = sm;
  char* Bs = sm + 16384;
  const int K = 2048;
  int tid = threadIdx.x;
  int lane = tid & 63, wv = tid >> 6;
  int lo = lane & 15, hi = lane >> 4;
  int wm = wv >> 1, wn = wv & 1;
  int bm = blockIdx.x, bn = blockIdx.y;
  f32x4 acc[4][4] = {};
  const u16* Abase = A + (size_t)bm * 128 * K;
  const u16* Bbase = BT + (size_t)bn * 128 * K;
  for (int kt = 0; kt < K / 64; ++kt) {
#pragma unroll
    for (int i = 0; i < 4; ++i) {
      int s = i * 4 + wv;
      int o = s * 1024 + lane * 16;
      int row = o >> 7, wb = o & 127;
      gload16((const char*)(Abase + (size_t)row * K + kt * 64) + SW(row, wb), As + s * 1024);
      gload16((const char*)(Bbase + (size_t)row * K + kt * 64) + SW(row, wb), Bs + s * 1024);
    }
    __syncthreads();
#pragma unroll
    for (int kk = 0; kk < 2; ++kk) {
      bf16x8 af[4], bfr[4];
#pragma unroll
      for (int i = 0; i < 4; ++i) {
        int r = wm * 64 + i * 16 + lo;
        af[i] = *(const bf16x8*)(As + r * 128 + SW(r, kk * 64 + hi * 16));
      }
#pragma unroll
      for (int j = 0; j < 4; ++j) {
        int r = wn * 64 + j * 16 + lo;
        bfr[j] = *(const bf16x8*)(Bs + r * 128 + SW(r, kk * 64 + hi * 16));
      }
#pragma unroll
      for (int i = 0; i < 4; ++i)
#pragma unroll
        for (int j = 0; j < 4; ++j) acc[i][j] = MFMA16(af[i], bfr[j], acc[i][j]);
    }
    __syncthreads();
  }
  int m0 = bm * 128 + wm * 64;
  int n0 = bn * 128 + wn * 64;
#pragma unroll
  for (int i = 0; i < 4; ++i) {
#pragma unroll
    for (int j = 0; j < 4; ++j) {
      int n = n0 + j * 16 + lo;
#pragma unroll
      for (int r = 0; r < 4; ++r) {
        int m = m0 + i * 16 + hi * 4 + r;
        float v = acc[i][j][r];
        if (EPI == 0) {
          int h = n >> 7, d = n & 127;
          float g = (h < 4) ? gate[(size_t)m * 4 + h] : 1.0f;
          v *= 0.08838834764831845f * g;  // 1/sqrt(128) and pre-softmax gate
          int b = m >> 11, t = m & 2047;
          ((u16*)outp)[((size_t)((b * 16 + h) * 2048 + t)) * 128 + d] = bf16rne(v);
        } else {
          ((float*)outp)[(size_t)m * 2048 + n] = v;  // 16 lanes -> 64B coalesced
        }
      }
    }
  }
}

// dual-B GEMM: acc1 = A*B1, acc2 = A*B2; epilogue: val = w*acc1 + (1-w)*acc2
// ISV=0: write f32 + bf16 both (B,H,T,DH).  ISV=1: f32 (B,H,T,DH), bf16 (B,H,DH,T)
template <int ISV>
__global__ __launch_bounds__(256) void gemm_bt_dual(const u16* __restrict__ A,
                                                    const u16* __restrict__ B1,
                                                    const u16* __restrict__ B2,
                                                    const float* __restrict__ blend,
                                                    float* __restrict__ fout,
                                                    u16* __restrict__ bout) {
  __shared__ __align__(16) char sm[49152];
  char* As = sm;
  char* Bs = sm + 16384;
  char* Cs = sm + 32768;
  const int K = 2048;
  int tid = threadIdx.x;
  int lane = tid & 63, wv = tid >> 6;
  int lo = lane & 15, hi = lane >> 4;
  int wm = wv >> 1, wn = wv & 1;
  int bm = blockIdx.x, bn = blockIdx.y;
  f32x4 ac1[4][4] = {};
  f32x4 ac2[4][4] = {};
  const u16* Abase = A + (size_t)bm * 128 * K;
  const u16* B1base = B1 + (size_t)bn * 128 * K;
  const u16* B2base = B2 + (size_t)bn * 128 * K;
  for (int kt = 0; kt < K / 64; ++kt) {
#pragma unroll
    for (int i = 0; i < 4; ++i) {
      int s = i * 4 + wv;
      int o = s * 1024 + lane * 16;
      int row = o >> 7, wb = o & 127;
      gload16((const char*)(Abase + (size_t)row * K + kt * 64) + SW(row, wb), As + s * 1024);
      gload16((const char*)(B1base + (size_t)row * K + kt * 64) + SW(row, wb), Bs + s * 1024);
      gload16((const char*)(B2base + (size_t)row * K + kt * 64) + SW(row, wb), Cs + s * 1024);
    }
    __syncthreads();
#pragma unroll
    for (int kk = 0; kk < 2; ++kk) {
      bf16x8 af[4], b1f[4], b2f[4];
#pragma unroll
      for (int i = 0; i < 4; ++i) {
        int r = wm * 64 + i * 16 + lo;
        af[i] = *(const bf16x8*)(As + r * 128 + SW(r, kk * 64 + hi * 16));
      }
#pragma unroll
      for (int j = 0; j < 4; ++j) {
        int r = wn * 64 + j * 16 + lo;
        b1f[j] = *(const bf16x8*)(Bs + r * 128 + SW(r, kk * 64 + hi * 16));
        b2f[j] = *(const bf16x8*)(Cs + r * 128 + SW(r, kk * 64 + hi * 16));
      }
#pragma unroll
      for (int i = 0; i < 4; ++i)
#pragma unroll
        for (int j = 0; j < 4; ++j) {
          ac1[i][j] = MFMA16(af[i], b1f[j], ac1[i][j]);
          ac2[i][j] = MFMA16(af[i], b2f[j], ac2[i][j]);
        }
    }
    __syncthreads();
  }
  int m0 = bm * 128 + wm * 64;
  int n0 = bn * 128 + wn * 64;
#pragma unroll
  for (int i = 0; i < 4; ++i) {
#pragma unroll
    for (int j = 0; j < 4; ++j) {
      int n = n0 + j * 16 + lo;
      int h = n >> 7, d = n & 127;
#pragma unroll
      for (int r = 0; r < 4; ++r) {
        int m = m0 + i * 16 + hi * 4 + r;
        float w = blend[(size_t)m * 16 + h];
        float v = w * ac1[i][j][r] + (1.f - w) * ac2[i][j][r];
        int b = m >> 11, t = m & 2047;
        size_t oi = ((size_t)((b * 16 + h) * 2048 + t)) * 128 + d;
        fout[oi] = v;
        if (ISV)
          bout[((size_t)((b * 16 + h) * 128 + d)) * 2048 + t] = bf16rne(v);
        else
          bout[oi] = bf16rne(v);
      }
    }
  }
}

// ------------------------------------------------------------ flash attention
// q: (B*H, T, DH) bf16 (pre-scaled by gate/sqrt(DH));  k: (B*H, T, DH) bf16;
// vt: (B*H, DH, T) bf16;  out: (B, T, H*DH) bf16
// block: 256 thr (4 waves), 128 q rows; wave owns 32 q rows; KV tile = 64 keys.
// No-max online softmax (scores bounded for this problem).
__global__ __launch_bounds__(256) void attn_kernel(const u16* __restrict__ qg,
                                                   const u16* __restrict__ kg,
                                                   const u16* __restrict__ vtg,
                                                   u16* __restrict__ aout) {
  __shared__ __align__(16) char sm[49152];
  char* Ks = sm;            // [64 keys][256B] swizzled
  char* VTs = sm + 16384;   // [128 d][128B] swizzled
  char* Ps = sm + 32768;    // 4 waves x [32 q][128B] swizzled
  int tid = threadIdx.x, lane = tid & 63, wv = tid >> 6;
  int lo = lane & 15, hi = lane >> 4;
  int bh = blockIdx.y;
  int q0 = blockIdx.x * 128 + wv * 32;
  const u16* qrow = qg + (size_t)bh * 2048 * 128;
  bf16x8 qf[2][4];
#pragma unroll
  for (int g = 0; g < 2; ++g)
#pragma unroll
    for (int dc = 0; dc < 4; ++dc)
      qf[g][dc] = *(const bf16x8*)(qrow + (size_t)(q0 + g * 16 + lo) * 128 + dc * 32 + hi * 8);
  float lsum[2] = {0.f, 0.f};
  f32x4 oacc[8][2] = {};
  char* Pw = Ps + wv * 4096;
  const char* kbase = (const char*)(kg + (size_t)bh * 2048 * 128);
  const char* vtbase = (const char*)(vtg + (size_t)bh * 128 * 2048);
  for (int kv = 0; kv < 2048; kv += 64) {
    const char* Kt = kbase + (size_t)kv * 256;
    const char* Vt = vtbase + (size_t)kv * 2;
#pragma unroll
    for (int i = 0; i < 4; ++i) {
      int s = i * 4 + wv;
      int o = s * 1024 + lane * 16;
      {  // K tile: 64 rows x 256B
        int row = o >> 8, wb = o & 255;
        gload16(Kt + (size_t)row * 256 + SW(row, wb), Ks + s * 1024);
      }
      {  // V^T tile: 128 rows x 128B (global row stride = T*2 = 4096B)
        int row = o >> 7, wb = o & 127;
        gload16(Vt + (size_t)row * 4096 + SW(row, wb), VTs + s * 1024);
      }
    }
    __syncthreads();
    // S^T = K . Q^T via mfma(A=K, B=Q): D[key][q], col=lane&15=q (stats lane-local)
#pragma unroll
    for (int kgi = 0; kgi < 4; ++kgi) {
      bf16x8 kf[4];
#pragma unroll
      for (int dc = 0; dc < 4; ++dc) {
        int r = kgi * 16 + lo;
        kf[dc] = *(const bf16x8*)(Ks + r * 256 + SW(r, dc * 64 + hi * 16));
      }
#pragma unroll
      for (int g = 0; g < 2; ++g) {
        f32x4 s4 = {};
#pragma unroll
        for (int dc = 0; dc < 4; ++dc) s4 = MFMA16(kf[dc], qf[g][dc], s4);
        float p0 = __expf(s4[0]), p1 = __expf(s4[1]);
        float p2 = __expf(s4[2]), p3 = __expf(s4[3]);
        lsum[g] += (p0 + p1) + (p2 + p3);
        int pr = g * 16 + lo;
        u32 w0 = (u32)bf16rne(p0) | ((u32)bf16rne(p1) << 16);
        u32 w1 = (u32)bf16rne(p2) | ((u32)bf16rne(p3) << 16);
        int cb = kgi * 32 + hi * 8;  // byte col of key kgi*16+hi*4
        *(u32*)(Pw + pr * 128 + SW(pr, cb)) = w0;
        *(u32*)(Pw + pr * 128 + SW(pr, cb + 4)) = w1;
      }
    }
    // PV: out^T += V^T . P^T via mfma(A=V^T, B=P): D[d][q]
    bf16x8 pb[2][2];
#pragma unroll
    for (int g = 0; g < 2; ++g)
#pragma unroll
      for (int kc = 0; kc < 2; ++kc) {
        int r = g * 16 + lo;
        pb[g][kc] = *(const bf16x8*)(Pw + r * 128 + SW(r, kc * 64 + hi * 16));
      }
#pragma unroll
    for (int mg = 0; mg < 8; ++mg) {
#pragma unroll
      for (int kc = 0; kc < 2; ++kc) {
        int r = mg * 16 + lo;
        bf16x8 va = *(const bf16x8*)(VTs + r * 128 + SW(r, kc * 64 + hi * 16));
        oacc[mg][0] = MFMA16(va, pb[0][kc], oacc[mg][0]);
        oacc[mg][1] = MFMA16(va, pb[1][kc], oacc[mg][1]);
      }
    }
    __syncthreads();
  }
  float rinv[2];
#pragma unroll
  for (int g = 0; g < 2; ++g) {
    float s = lsum[g];
    s += __shfl_xor(s, 16);
    s += __shfl_xor(s, 32);
    rinv[g] = 1.f / s;
  }
  int b = bh >> 4, h = bh & 15;
#pragma unroll
  for (int g = 0; g < 2; ++g) {
    int t = q0 + g * 16 + lo;
    u16* orow = aout + ((size_t)(b * 2048 + t)) * 2048 + h * 128;
#pragma unroll
    for (int mg = 0; mg < 8; ++mg) {
      int d = mg * 16 + hi * 4;
      ushort4 o4;
      o4.x = bf16rne(oacc[mg][g][0] * rinv[g]);
      o4.y = bf16rne(oacc[mg][g][1] * rinv[g]);
      o4.z = bf16rne(oacc[mg][g][2] * rinv[g]);
      o4.w = bf16rne(oacc[mg][g][3] * rinv[g]);
      *(ushort4*)(orow + d) = o4;
    }
  }
}

// ---------------------------------------------------------------- launcher
extern "C" void kernel_launch(void* const* d_in, const int* in_sizes, int n_in,
                              void* d_out, int out_size, void* d_ws, size_t ws_size,
                              hipStream_t stream) {
  const float* x = (const float*)d_in[0];
  const float* msk = (const float*)d_in[1];
  const float* Wq = (const float*)d_in[2];
  const float* Wkc = (const float*)d_in[3];
  const float* Wvc = (const float*)d_in[4];
  const float* Wkt = (const float*)d_in[5];
  const float* Wvt = (const float*)d_in[6];
  const float* Wb = (const float*)d_in[7];
  const float* bb = (const float*)d_in[8];
  const float* Wo = (const float*)d_in[9];
  const float* Wg1 = (const float*)d_in[10];
  const float* bg1 = (const float*)d_in[11];
  const float* Wg2 = (const float*)d_in[12];
  const float* bg2 = (const float*)d_in[13];

  char* ws = (char*)d_ws;
  u16* xb = (u16*)(ws + 0);                 // 16.8MB, reused as attn-out later
  u16* WqT = (u16*)(ws + 16777216);         // 8.4MB, reused for Wout^T later
  u16* WkcT = (u16*)(ws + 25165824);
  u16* WktT = (u16*)(ws + 33554432);
  u16* WvcT = (u16*)(ws + 41943040);
  u16* WvtT = (u16*)(ws + 50331648);
  u16* qb = (u16*)(ws + 58720256);
  u16* kb = (u16*)(ws + 75497472);
  u16* vtb = (u16*)(ws + 92274688);
  float* blend = (float*)(ws + 109051904);
  float* gate = (float*)(ws + 109314048);   // end = 109379584 bytes

  float* out_o = (float*)d_out;
  float* out_k = out_o + 8388608;
  float* out_v = out_o + 16777216;

  dim3 tb(32, 8), tg(64, 64), gg(32, 16);

  cvtx_kernel<<<8192, 256, 0, stream>>>(x, xb);
  wtrans_kernel<<<tg, tb, 0, stream>>>(Wq, WqT);
  wtrans_kernel<<<tg, tb, 0, stream>>>(Wkc, WkcT);
  wtrans_kernel<<<tg, tb, 0, stream>>>(Wkt, WktT);
  wtrans_kernel<<<tg, tb, 0, stream>>>(Wvc, WvcT);
  wtrans_kernel<<<tg, tb, 0, stream>>>(Wvt, WvtT);
  gate_kernel<<<2, 256, 0, stream>>>(msk, Wg1, bg1, Wg2, bg2, gate);
  blend_kernel<<<256, 256, 0, stream>>>(x, Wb, bb, blend);

  gemm_bt<0><<<gg, 256, 0, stream>>>(xb, WqT, gate, (void*)qb);
  gemm_bt_dual<0><<<gg, 256, 0, stream>>>(xb, WkcT, WktT, blend, out_k, kb);
  gemm_bt_dual<1><<<gg, 256, 0, stream>>>(xb, WvcT, WvtT, blend, out_v, vtb);

  // Wq^T slot is free now; put Wout^T there (stream-ordered, safe)
  wtrans_kernel<<<tg, tb, 0, stream>>>(Wo, WqT);

  // xb slot is free now; attention writes its (B,T,D) bf16 output there
  u16* ao = xb;
  attn_kernel<<<dim3(16, 32), 256, 0, stream>>>(qb, kb, vtb, ao);

  gemm_bt<1><<<gg, 256, 0, stream>>>(ao, WqT, (const float*)nullptr, (void*)out_o);
}